// Round 3
// baseline (137.262 us; speedup 1.0000x reference)
//
#include <hip/hip_runtime.h>

#define NTOK 2048
#define DD   128
#define CHK  64
#define NCH  32
#define EW   16

typedef __attribute__((ext_vector_type(8))) short bf16x8;
typedef __attribute__((ext_vector_type(4))) float f32x4;
typedef unsigned short u16;
typedef unsigned int u32;

#define MFMA(a,b,c) __builtin_amdgcn_mfma_f32_16x16x32_bf16(a,b,c,0,0,0)

__device__ __forceinline__ u16 f2bf(float f){
  union { float f; unsigned u; } x; x.f = f;
  return (u16)((x.u + 0x7fffu + ((x.u >> 16) & 1u)) >> 16);
}
// XOR-swizzle 16B units within 128B windows by row&7
__device__ __forceinline__ int swz(int r, int c, int re){
  int b = (r*re + c)*2;
  return b ^ ((r & 7) << 4);
}
__device__ __forceinline__ void lds_w1(u16* a, int r, int c, int re, u16 v){
  *(u16*)((char*)a + swz(r,c,re)) = v;
}
__device__ __forceinline__ void lds_w4(u16* a, int r, int c, int re, ushort4 v){
  *(ushort4*)((char*)a + swz(r,c,re)) = v;
}
__device__ __forceinline__ bf16x8 lds_r8(const u16* a, int r, int c, int re){
  return *(const bf16x8*)((const char*)a + swz(r,c,re));
}
__device__ __forceinline__ void gld16(const float* g, float* l){
  __builtin_amdgcn_global_load_lds((const __attribute__((address_space(1))) u32*)g,
                                   (__attribute__((address_space(3))) u32*)l, 16, 0, 0);
}

__global__ __launch_bounds__(256, 2) void gla_fused(
    const float* __restrict__ Qg, const float* __restrict__ Kg,
    const float* __restrict__ Vg, const float* __restrict__ Gg,
    float* __restrict__ Og)
{
  __shared__ float Kraw[CHK*DD];   // raw K chunk (next), source-swizzled   32 KB
  __shared__ u16 Kh [CHK*DD];      // K_hat [s][d], swz                     16 KB
  __shared__ u16 KhT[DD*CHK];      // K_hat^T [d][s], swz                   16 KB
  __shared__ u16 VT [EW*CHK];      // V^T slice [e][s], swz                  2 KB
  __shared__ u16 ST [EW*DD];       // S^T [e][d], swz (bf16 snapshot)        4 KB
  __shared__ u16 Pb [CHK*CHK];     // masked P [t][s], swz                   8 KB

  const int tid = threadIdx.x;
  const int w = tid >> 6, l = tid & 63, lr = l & 15, lh = l >> 4;
  // blockIdx bits: [0:2]=head-low (XCD id), [3:5]=e-slice, [6:8]=head-high
  // -> all 8 e-slices of a head land on the same XCD and share its L2.
  const int bh = (blockIdx.x & 7) | (((blockIdx.x >> 6) & 7) << 3);
  const int e0 = ((blockIdx.x >> 3) & 7) * EW;

  const float* Qh  = Qg + (size_t)bh*NTOK*DD;
  const float* Kgh = Kg + (size_t)bh*NTOK*DD;
  const float* Vh  = Vg + (size_t)bh*NTOK*DD;
  const float* Gh  = Gg + (size_t)bh*NTOK;
  float* Oh = Og + (size_t)bh*NTOK*DD;

  f32x4 S00 = {}, S10 = {};        // S slice [d: w*32..+32][e: 0..16], MFMA C-layout
  float4 qpre[8];
  float4 vst;
  float  gst;

  auto prefetch = [&](int c){
    const int t0 = c*CHK;
    #pragma unroll
    for (int i=0;i<8;++i){        // K chunk: 2048 16B-units, src col pre-swizzled
      int u = i*256 + tid;
      int s = u >> 5, cu = u & 31;
      int src = (cu & 24) | ((cu & 7) ^ (s & 7));
      gld16(Kgh + (size_t)(t0+s)*DD + src*4, Kraw + u*4);
    }
    // V slice -> regs (coalesced float4 per thread)
    vst = *(const float4*)(Vh + (size_t)(t0 + (tid>>2))*DD + e0 + (tid&3)*4);
    // G -> regs (redundant per wave, 256B, L1)
    gst = Gh[t0 + l];
    // Q A-fragments straight to regs
    const float* qp = Qh + (size_t)(t0 + w*16 + lr)*DD + lh*8;
    #pragma unroll
    for (int ks=0;ks<4;++ks){
      qpre[ks*2]   = *(const float4*)(qp + ks*32);
      qpre[ks*2+1] = *(const float4*)(qp + ks*32 + 4);
    }
  };

  prefetch(0);

  for (int c=0; c<NCH; ++c){
    __syncthreads();   // sync A: Kraw ready (vmcnt drained); bf16 bufs free

    // gate math, redundant per wave
    float li = 1.f/(1.f + expf(-gst));
    float x  = log2f(li);
    #pragma unroll
    for (int off=1; off<64; off<<=1){
      float y = __shfl_up(x, off, 64);
      if (l >= off) x += y;
    }
    const float bl  = x;                              // b_t at t=l
    const float ckl = exp2f(-bl) * (1.f - li);        // k-hat scale, row s=l
    const float cq  = exp2f(__shfl(bl, w*16 + lr, 64));
    const float scc = exp2f(__shfl(bl, 63, 64));      // 2^{b_63}

    // ---- convert K -> Kh, KhT ----
    #pragma unroll
    for (int i=0;i<8;++i){
      float4 kf = *(const float4*)(Kraw + l*DD + w*32 + ((i ^ (l&7)) * 4));
      int d = w*32 + i*4;
      u16 b0=f2bf(kf.x*ckl), b1=f2bf(kf.y*ckl), b2=f2bf(kf.z*ckl), b3=f2bf(kf.w*ckl);
      lds_w4(Kh, l, d, DD, make_ushort4(b0,b1,b2,b3));
      lds_w1(KhT, d+0, l, CHK, b0);
      lds_w1(KhT, d+1, l, CHK, b1);
      lds_w1(KhT, d+2, l, CHK, b2);
      lds_w1(KhT, d+3, l, CHK, b3);
    }
    // ---- V regs -> VT ----
    {
      const int s = tid >> 2, eb = (tid & 3)*4;
      lds_w1(VT, eb+0, s, CHK, f2bf(vst.x));
      lds_w1(VT, eb+1, s, CHK, f2bf(vst.y));
      lds_w1(VT, eb+2, s, CHK, f2bf(vst.z));
      lds_w1(VT, eb+3, s, CHK, f2bf(vst.w));
    }
    // ---- snapshot S -> ST (bf16) ----
    {
      const int dbase = w*32 + lh*4;
      #pragma unroll
      for (int r=0;r<4;++r){
        lds_w1(ST, lr, dbase + r,      DD, f2bf(S00[r]));
        lds_w1(ST, lr, dbase + 16 + r, DD, f2bf(S10[r]));
      }
    }
    // ---- qA fragments ----
    bf16x8 qA[4];
    #pragma unroll
    for (int ks=0;ks<4;++ks){
      float4 a = qpre[ks*2], b = qpre[ks*2+1];
      bf16x8 t;
      t[0]=(short)f2bf(a.x*cq); t[1]=(short)f2bf(a.y*cq);
      t[2]=(short)f2bf(a.z*cq); t[3]=(short)f2bf(a.w*cq);
      t[4]=(short)f2bf(b.x*cq); t[5]=(short)f2bf(b.y*cq);
      t[6]=(short)f2bf(b.z*cq); t[7]=(short)f2bf(b.w*cq);
      qA[ks] = t;
    }
    __syncthreads();   // sync B: bf16 bufs ready; raw/regs free -> prefetch next
    if (c+1 < NCH) prefetch(c+1);

    // ---- O1 = Qt*S_in ; P = Qt*Kh^T ----
    f32x4 oacc = {};
    f32x4 p0 = {}, p1 = {}, p2 = {}, p3 = {};
    #pragma unroll
    for (int ks=0;ks<4;++ks){
      const int kk = ks*32 + lh*8;
      bf16x8 a = qA[ks];
      oacc = MFMA(a, lds_r8(ST, lr, kk, DD), oacc);
      p0 = MFMA(a, lds_r8(Kh, lr,    kk, DD), p0);
      p1 = MFMA(a, lds_r8(Kh, 16+lr, kk, DD), p1);
      p2 = MFMA(a, lds_r8(Kh, 32+lr, kk, DD), p2);
      p3 = MFMA(a, lds_r8(Kh, 48+lr, kk, DD), p3);
    }
    // ---- causal mask -> Pb (own rows only) ----
    {
      const int t = w*16 + lh*4;
      #pragma unroll
      for (int r=0;r<4;++r){
        int tt = t + r;
        lds_w1(Pb, tt, lr,    CHK, f2bf((lr    <= tt) ? p0[r] : 0.f));
        lds_w1(Pb, tt, 16+lr, CHK, f2bf((16+lr <= tt) ? p1[r] : 0.f));
        lds_w1(Pb, tt, 32+lr, CHK, f2bf((32+lr <= tt) ? p2[r] : 0.f));
        lds_w1(Pb, tt, 48+lr, CHK, f2bf((48+lr <= tt) ? p3[r] : 0.f));
      }
    }
    // wave reads only its own Pb rows -> wave-local wait, no barrier
    asm volatile("s_waitcnt lgkmcnt(0)" ::: "memory");
    __builtin_amdgcn_sched_barrier(0);

    // ---- O2 += P*V ; S += Khat^T * V ----
    #pragma unroll
    for (int k2=0;k2<2;++k2){
      const int kk = k2*32 + lh*8;
      bf16x8 vb  = lds_r8(VT, lr, kk, CHK);
      bf16x8 pa  = lds_r8(Pb, w*16 + lr, kk, CHK);
      oacc = MFMA(pa, vb, oacc);
      bf16x8 ka0 = lds_r8(KhT, w*32 + lr,      kk, CHK);
      bf16x8 ka1 = lds_r8(KhT, w*32 + 16 + lr, kk, CHK);
      S00 = MFMA(ka0, vb, S00);
      S10 = MFMA(ka1, vb, S10);
    }
    // S_new = 2^{b63} * (S_old + Khat^T V)
    #pragma unroll
    for (int r=0;r<4;++r){ S00[r]*=scc; S10[r]*=scc; }

    // ---- write O chunk (fp32) ----
    {
      float* op = Oh + (size_t)(c*CHK + w*16 + lh*4)*DD + e0;
      #pragma unroll
      for (int r=0;r<4;++r) op[r*DD + lr] = oacc[r];
    }
  }
}

extern "C" void kernel_launch(void* const* d_in, const int* in_sizes, int n_in,
                              void* d_out, int out_size, void* d_ws, size_t ws_size,
                              hipStream_t stream)
{
  const float* q = (const float*)d_in[0];
  const float* k = (const float*)d_in[1];
  const float* v = (const float*)d_in[2];
  const float* g = (const float*)d_in[3];
  float* out = (float*)d_out;

  gla_fused<<<dim3(512), dim3(256), 0, stream>>>(q, k, v, g, out);
}